// Round 9
// baseline (55.447 us; speedup 1.0000x reference)
//
#include <hip/hip_runtime.h>
#include <math.h>

#define T_TOK 8192
#define DDIM  4096
#define NEXP  64
#define TOPK  8
#define WAVES 8
#define STEPS 16          // 512 k per wave (DDIM / WAVES / 32)

typedef __attribute__((ext_vector_type(8))) _Float16 half8;
typedef __attribute__((ext_vector_type(4))) float f32x4;

#define RS 2048.0f

// ---- K0: pack gate_weight [E][D] f32 into MFMA B-fragment order, split f16.
// wpk[(kt*4 + n)*2 + p][lane][8], p=0: h0, p=1: (w-h0)*2048.
// B frag (16x16x32): expert col = n*16 + (lane&15), k = kt*32 + (lane>>4)*8 + j.
__global__ __launch_bounds__(256) void pack_w(
    const float* __restrict__ gw, _Float16* __restrict__ wpk)
{
    const int g    = blockIdx.x * 256 + threadIdx.x;
    const int lane = g & 63;
    const int n    = (g >> 6) & 3;
    const int kt   = g >> 8;                     // 0..127
    const int e    = n * 16 + (lane & 15);
    const int k    = kt * 32 + (lane >> 4) * 8;

    const float* src = gw + (size_t)e * DDIM + k;
    float4 v0 = *reinterpret_cast<const float4*>(src);
    float4 v1 = *reinterpret_cast<const float4*>(src + 4);
    const float v[8] = {v0.x, v0.y, v0.z, v0.w, v1.x, v1.y, v1.z, v1.w};

    half8 h0, h1;
    #pragma unroll
    for (int j = 0; j < 8; j++) {
        _Float16 a = (_Float16)v[j];
        h0[j] = a;
        h1[j] = (_Float16)((v[j] - (float)a) * RS);
    }
    size_t base = ((size_t)(kt * 4 + n) * 2) * 512;
    *reinterpret_cast<half8*>(wpk + base + lane * 8)       = h0;
    *reinterpret_cast<half8*>(wpk + base + 512 + lane * 8) = h1;
}

// ---- K1: fused logits GEMM + reduce + sigmoid + top-8 ----
// 512 thr = 8 waves, block = 32 tokens, wave = k-slice of 512.
// Pipeline (per step, issue order matters for in-order vmcnt):
//   1. issue B(st+1)            (oldest new loads -> B wait stays cheap)
//   2. issue A(st+3)            (young; never forced by B waits)
//   3. convert A(st+1) -> ac[nxt]  (waits A(st+1): 2 full steps of cover)
//   4. MFMA with ac[cur], bf[cur]  (waits B(st): 1 step of cover, L2-resident)
// No launch-bounds occupancy clause: grid 256 = 1 block/CU regardless; let
// VGPRs float so all pipeline arrays stay live (R8's 64-VGPR cap killed it).
__global__ __launch_bounds__(512) void gemm_topk(
    const float* __restrict__ x, const _Float16* __restrict__ wpk,
    const float* __restrict__ bias, float* __restrict__ out)
{
    __shared__ float red[WAVES][32][NEXP];       // 64 KB

    const int tid  = threadIdx.x;
    const int lane = tid & 63;
    const int wv   = tid >> 6;                   // k-slice
    const int tok0 = blockIdx.x * 32;
    const int am   = lane & 15;
    const int ag   = lane >> 4;

    const float* xr0 = x + (size_t)(tok0 + am) * DDIM + wv * (DDIM / WAVES) + ag * 8;
    const float* xr1 = xr0 + (size_t)16 * DDIM;
    const _Float16* bbase = wpk + (size_t)(wv * STEPS) * 8 * 512 + lane * 8;

    f32x4 aH[2][4], aM[2][4];
    #pragma unroll
    for (int t = 0; t < 2; t++)
        #pragma unroll
        for (int n = 0; n < 4; n++) {
            aH[t][n] = (f32x4){0.f, 0.f, 0.f, 0.f};
            aM[t][n] = (f32x4){0.f, 0.f, 0.f, 0.f};
        }

    float4 av[3][4];      // raw A, rotating depth-3 (holds st+1..st+3)
    half8  bf[2][8];      // B double buffer
    half8  ac0[2][2], ac1[2][2];   // converted A [st&1][tile], planes 0/1

    // ---- prologue ----
    #pragma unroll
    for (int n = 0; n < 4; n++) {                 // B(0) first (oldest)
        bf[0][2 * n]     = *reinterpret_cast<const half8*>(bbase + n * 1024);
        bf[0][2 * n + 1] = *reinterpret_cast<const half8*>(bbase + n * 1024 + 512);
    }
    #pragma unroll
    for (int st = 0; st < 3; st++) {              // A(0..2)
        av[st][0] = *reinterpret_cast<const float4*>(xr0 + st * 32);
        av[st][1] = *reinterpret_cast<const float4*>(xr0 + st * 32 + 4);
        av[st][2] = *reinterpret_cast<const float4*>(xr1 + st * 32);
        av[st][3] = *reinterpret_cast<const float4*>(xr1 + st * 32 + 4);
    }
    // convert A(0) -> ac[0]
    #pragma unroll
    for (int t = 0; t < 2; t++) {
        const float* vv = reinterpret_cast<const float*>(&av[0][2 * t]);
        #pragma unroll
        for (int j = 0; j < 8; j++) {
            float v = vv[j];
            _Float16 h = (_Float16)v;
            ac0[0][t][j] = h;
            ac1[0][t][j] = (_Float16)((v - (float)h) * RS);
        }
    }

    #pragma unroll
    for (int st = 0; st < STEPS; st++) {
        const int cur = st & 1;
        const int nxt = cur ^ 1;

        if (st + 1 < STEPS) {                     // 1. B(st+1) — issue FIRST
            const _Float16* bp = bbase + (size_t)(st + 1) * 8 * 512;
            #pragma unroll
            for (int n = 0; n < 4; n++) {
                bf[nxt][2 * n]     = *reinterpret_cast<const half8*>(bp + n * 1024);
                bf[nxt][2 * n + 1] = *reinterpret_cast<const half8*>(bp + n * 1024 + 512);
            }
        }
        if (st + 3 < STEPS) {                     // 2. A(st+3) — young, uncoupled
            const int ap = (st + 3) % 3;
            av[ap][0] = *reinterpret_cast<const float4*>(xr0 + (st + 3) * 32);
            av[ap][1] = *reinterpret_cast<const float4*>(xr0 + (st + 3) * 32 + 4);
            av[ap][2] = *reinterpret_cast<const float4*>(xr1 + (st + 3) * 32);
            av[ap][3] = *reinterpret_cast<const float4*>(xr1 + (st + 3) * 32 + 4);
        }
        if (st + 1 < STEPS) {                     // 3. convert A(st+1) -> ac[nxt]
            const int as = (st + 1) % 3;
            #pragma unroll
            for (int t = 0; t < 2; t++) {
                const float* vv = reinterpret_cast<const float*>(&av[as][2 * t]);
                #pragma unroll
                for (int j = 0; j < 8; j++) {
                    float v = vv[j];
                    _Float16 h = (_Float16)v;
                    ac0[nxt][t][j] = h;
                    ac1[nxt][t][j] = (_Float16)((v - (float)h) * RS);
                }
            }
        }
        #pragma unroll                            // 4. MFMAs (wait B(st) only)
        for (int t = 0; t < 2; t++)
            #pragma unroll
            for (int n = 0; n < 4; n++) {
                aH[t][n] = __builtin_amdgcn_mfma_f32_16x16x32_f16(ac0[cur][t], bf[cur][2 * n],     aH[t][n], 0, 0, 0);
                aM[t][n] = __builtin_amdgcn_mfma_f32_16x16x32_f16(ac0[cur][t], bf[cur][2 * n + 1], aM[t][n], 0, 0, 0);
                aM[t][n] = __builtin_amdgcn_mfma_f32_16x16x32_f16(ac1[cur][t], bf[cur][2 * n],     aM[t][n], 0, 0, 0);
            }
    }

    // ---- dump plane-combined slice logits to LDS ----
    // C/D layout (m89): col = lane&15 (expert), row = (lane>>4)*4 + r (token)
    const float i1 = 1.0f / RS;
    #pragma unroll
    for (int t = 0; t < 2; t++)
        #pragma unroll
        for (int n = 0; n < 4; n++)
            #pragma unroll
            for (int r = 0; r < 4; r++)
                red[wv][t * 16 + ag * 4 + r][n * 16 + am]
                    = aH[t][n][r] + aM[t][n][r] * i1;
    __syncthreads();

    // ---- 8-slice reduce in place ----
    {
        const int tok = tid >> 4;                // 0..31
        const int c4  = tid & 15;
        float4 s0 = *reinterpret_cast<const float4*>(&red[0][tok][c4 * 4]);
        #pragma unroll
        for (int s = 1; s < WAVES; s++) {
            float4 v = *reinterpret_cast<const float4*>(&red[s][tok][c4 * 4]);
            s0.x += v.x; s0.y += v.y; s0.z += v.z; s0.w += v.w;
        }
        *reinterpret_cast<float4*>(&red[0][tok][c4 * 4]) = s0;
    }
    __syncthreads();

    // ---- top-8: wave wv handles tokens wv*4 .. wv*4+3, lane = expert ----
    const float bsv = bias[lane];
    #pragma unroll
    for (int ti = 0; ti < 4; ti++) {
        const int tk = wv * 4 + ti;
        float logit  = red[0][tk][lane];
        float score  = 1.f / (1.f + expf(-logit));
        float biased = score + bsv;
        float my_sc = 0.f; int my_idx = 0; float ssum = 0.f;
        #pragma unroll
        for (int j = 0; j < TOPK; j++) {
            float vb = biased; int ib = lane;
            #pragma unroll
            for (int off = 32; off >= 1; off >>= 1) {
                float ov = __shfl_xor(vb, off);
                int   oi = __shfl_xor(ib, off);
                if (ov > vb || (ov == vb && oi < ib)) { vb = ov; ib = oi; }
            }
            float s_sel = __shfl(score, ib);
            ssum += s_sel;
            if (lane == j) { my_idx = ib; my_sc = s_sel; }
            if (lane == ib) biased = -INFINITY;
        }
        if (lane < TOPK) {
            out[(size_t)(tok0 + tk) * TOPK + lane] = (float)my_idx;           // indices as f32
            out[(size_t)T_TOK * TOPK + (size_t)(tok0 + tk) * TOPK + lane]
                = my_sc / (ssum + 1e-20f);                                    // weights
        }
    }
}

extern "C" void kernel_launch(void* const* d_in, const int* in_sizes, int n_in,
                              void* d_out, int out_size, void* d_ws, size_t ws_size,
                              hipStream_t stream) {
    (void)in_sizes; (void)n_in; (void)out_size; (void)ws_size;
    const float* x    = (const float*)d_in[0];
    const float* gw   = (const float*)d_in[1];
    const float* bias = (const float*)d_in[2];
    float* out = (float*)d_out;
    _Float16* wpk = (_Float16*)d_ws;             // 1 MiB packed W frags

    pack_w<<<128, 256, 0, stream>>>(gw, wpk);
    gemm_topk<<<T_TOK / 32, 512, 0, stream>>>(x, wpk, bias, out);
}

// Round 10
// 54.393 us; speedup vs baseline: 1.0194x; 1.0194x over previous
//
#include <hip/hip_runtime.h>
#include <math.h>
#include <stdint.h>

#define T_TOK 8192
#define DDIM  4096
#define NEXP  64
#define TOPK  8
#define WAVES 8
#define STEPS 16          // 512 k per wave slice (DDIM / WAVES / 32)
#define RS    2048.0f

typedef __attribute__((ext_vector_type(8))) _Float16 half8;
typedef __attribute__((ext_vector_type(4))) float f32x4;
typedef __attribute__((address_space(3))) uint32_t lds_u32;
typedef const __attribute__((address_space(1))) uint32_t glb_u32;

// ---- K0: pack gate_weight [E][D] f32 into MFMA B-fragment order, split f16.
// wpk[(kt*4 + n)*2 + p][lane][8], p=0: h0, p=1: (w-h0)*2048.
__global__ __launch_bounds__(256) void pack_w(
    const float* __restrict__ gw, _Float16* __restrict__ wpk)
{
    const int g    = blockIdx.x * 256 + threadIdx.x;
    const int lane = g & 63;
    const int n    = (g >> 6) & 3;
    const int kt   = g >> 8;                     // 0..127
    const int e    = n * 16 + (lane & 15);
    const int k    = kt * 32 + (lane >> 4) * 8;

    const float* src = gw + (size_t)e * DDIM + k;
    float4 v0 = *reinterpret_cast<const float4*>(src);
    float4 v1 = *reinterpret_cast<const float4*>(src + 4);
    const float v[8] = {v0.x, v0.y, v0.z, v0.w, v1.x, v1.y, v1.z, v1.w};

    half8 h0, h1;
    #pragma unroll
    for (int j = 0; j < 8; j++) {
        _Float16 a = (_Float16)v[j];
        h0[j] = a;
        h1[j] = (_Float16)((v[j] - (float)a) * RS);
    }
    size_t base = ((size_t)(kt * 4 + n) * 2) * 512;
    *reinterpret_cast<half8*>(wpk + base + lane * 8)       = h0;
    *reinterpret_cast<half8*>(wpk + base + 512 + lane * 8) = h1;
}

// ---- K1: fused logits GEMM + reduce + sigmoid + top-8 ----
// 512 thr = 8 waves, block = 16 tokens, wave = k-slice of 512 (16 steps x 32k).
// A path: global_load_lds FIFO, 2 steps ahead, per-wave private 3-slot ring.
// Each lane's staged 32B IS its MFMA A-fragment (no layout transform).
// vmcnt discipline (order pinned by asm memory fences):
//   prologue: A(0)[2] A(1)[2]
//   step st:  [wait A(st)] [ds_read+cvt] [B(st) x8] [fence] [A(st+2) x2] [MFMA]
//   younger-than-A(st): st=0 -> A(1)=2; 1<=st<15 -> B(st-1)+A(st+1)=10; st=15 -> B(14)=8.
__global__ __launch_bounds__(512, 4) void gemm_topk(
    const float* __restrict__ x, const _Float16* __restrict__ wpk,
    const float* __restrict__ bias, float* __restrict__ out)
{
    __shared__ float smem[WAVES * 3 * 512];      // 48 KB ring; red (32 KB) overlays after barrier

    const int tid  = threadIdx.x;
    const int lane = tid & 63;
    const int wv   = tid >> 6;                   // k-slice
    const int tok0 = blockIdx.x * 16;
    const int am   = lane & 15;                  // token row
    const int ag   = lane >> 4;                  // k-group

    float* ring = smem + wv * (3 * 512);
    const float* xr = x + (size_t)(tok0 + am) * DDIM + wv * (DDIM / WAVES) + ag * 8;
    const _Float16* bbase = wpk + (size_t)(wv * STEPS) * 8 * 512 + lane * 8;

    f32x4 aH[4], aM[4];
    #pragma unroll
    for (int n = 0; n < 4; n++) {
        aH[n] = (f32x4){0.f, 0.f, 0.f, 0.f};
        aM[n] = (f32x4){0.f, 0.f, 0.f, 0.f};
    }

#define ISSUE_A(st_, slot_) do {                                              \
        const float* _s = xr + (st_) * 32;                                    \
        __builtin_amdgcn_global_load_lds((glb_u32*)_s,                        \
            (lds_u32*)(ring + (slot_) * 512), 16, 0, 0);                      \
        __builtin_amdgcn_global_load_lds((glb_u32*)(_s + 4),                  \
            (lds_u32*)(ring + (slot_) * 512 + 256), 16, 0, 0);                \
    } while (0)

    // prologue: stage A(0)->slot0, A(1)->slot1
    ISSUE_A(0, 0);
    ISSUE_A(1, 1);

    #pragma unroll
    for (int st = 0; st < STEPS; st++) {
        if (st == 0)      asm volatile("s_waitcnt vmcnt(2)"  ::: "memory");
        else if (st < 15) asm volatile("s_waitcnt vmcnt(10)" ::: "memory");
        else              asm volatile("s_waitcnt vmcnt(8)"  ::: "memory");
        __builtin_amdgcn_sched_barrier(0);

        // ds_read own fragment back (conflict-free: contiguous b128 by lane)
        const float* slotp = ring + (st % 3) * 512;
        float4 v0 = *reinterpret_cast<const float4*>(slotp + lane * 4);
        float4 v1 = *reinterpret_cast<const float4*>(slotp + 256 + lane * 4);

        half8 a0, a1;
        {
            const float vv[8] = {v0.x, v0.y, v0.z, v0.w, v1.x, v1.y, v1.z, v1.w};
            #pragma unroll
            for (int j = 0; j < 8; j++) {
                float v = vv[j];
                _Float16 h = (_Float16)v;
                a0[j] = h;
                a1[j] = (_Float16)((v - (float)h) * RS);
            }
        }

        // B(st): 8 x b128 from packed frags (L2-resident)
        const _Float16* bp = bbase + (size_t)st * 4096;
        half8 B0[4], B1[4];
        #pragma unroll
        for (int n = 0; n < 4; n++) {
            B0[n] = *reinterpret_cast<const half8*>(bp + n * 1024);
            B1[n] = *reinterpret_cast<const half8*>(bp + n * 1024 + 512);
        }

        asm volatile("" ::: "memory");           // pin: B(st) issues before A(st+2)

        if (st + 2 < STEPS) {
            const int stn = st + 2;
            ISSUE_A(stn, stn % 3);
        }

        #pragma unroll
        for (int n = 0; n < 4; n++) {
            aH[n] = __builtin_amdgcn_mfma_f32_16x16x32_f16(a0, B0[n], aH[n], 0, 0, 0);
            aM[n] = __builtin_amdgcn_mfma_f32_16x16x32_f16(a0, B1[n], aM[n], 0, 0, 0);
            aM[n] = __builtin_amdgcn_mfma_f32_16x16x32_f16(a1, B0[n], aM[n], 0, 0, 0);
        }
    }
#undef ISSUE_A

    __syncthreads();                             // all ring reads done before red overlay

    // ---- write plane-combined slice logits into red = smem[0..32KB) ----
    // C/D layout (m89): col = lane&15 (expert), row = (lane>>4)*4 + r (token)
    {
        const float i1 = 1.0f / RS;
        float* red = smem;                       // [WAVES][16][64]
        #pragma unroll
        for (int n = 0; n < 4; n++)
            #pragma unroll
            for (int r = 0; r < 4; r++)
                red[(size_t)(wv * 16 + ag * 4 + r) * 64 + n * 16 + am]
                    = aH[n][r] + aM[n][r] * i1;
    }
    __syncthreads();

    // ---- 8-slice reduce in place ----
    if (tid < 256) {
        float* red = smem;
        const int tok = tid >> 4;                // 0..15
        const int c4  = tid & 15;
        float4 s0 = *reinterpret_cast<const float4*>(red + (size_t)tok * 64 + c4 * 4);
        #pragma unroll
        for (int s = 1; s < WAVES; s++) {
            float4 v = *reinterpret_cast<const float4*>(
                red + (size_t)(s * 16 + tok) * 64 + c4 * 4);
            s0.x += v.x; s0.y += v.y; s0.z += v.z; s0.w += v.w;
        }
        *reinterpret_cast<float4*>(red + (size_t)tok * 64 + c4 * 4) = s0;
    }
    __syncthreads();

    // ---- top-8: wave wv handles tokens wv*2, wv*2+1; lane = expert ----
    const float bsv = bias[lane];
    const float* red = smem;
    #pragma unroll
    for (int ti = 0; ti < 2; ti++) {
        const int tk = wv * 2 + ti;
        float logit  = red[(size_t)tk * 64 + lane];
        float score  = 1.f / (1.f + expf(-logit));
        float biased = score + bsv;
        float my_sc = 0.f; int my_idx = 0; float ssum = 0.f;
        #pragma unroll
        for (int j = 0; j < TOPK; j++) {
            float vb = biased; int ib = lane;
            #pragma unroll
            for (int off = 32; off >= 1; off >>= 1) {
                float ov = __shfl_xor(vb, off);
                int   oi = __shfl_xor(ib, off);
                if (ov > vb || (ov == vb && oi < ib)) { vb = ov; ib = oi; }
            }
            float s_sel = __shfl(score, ib);
            ssum += s_sel;
            if (lane == j) { my_idx = ib; my_sc = s_sel; }
            if (lane == ib) biased = -INFINITY;
        }
        if (lane < TOPK) {
            out[(size_t)(tok0 + tk) * TOPK + lane] = (float)my_idx;           // indices as f32
            out[(size_t)T_TOK * TOPK + (size_t)(tok0 + tk) * TOPK + lane]
                = my_sc / (ssum + 1e-20f);                                    // weights
        }
    }
}

extern "C" void kernel_launch(void* const* d_in, const int* in_sizes, int n_in,
                              void* d_out, int out_size, void* d_ws, size_t ws_size,
                              hipStream_t stream) {
    (void)in_sizes; (void)n_in; (void)out_size; (void)ws_size;
    const float* x    = (const float*)d_in[0];
    const float* gw   = (const float*)d_in[1];
    const float* bias = (const float*)d_in[2];
    float* out = (float*)d_out;
    _Float16* wpk = (_Float16*)d_ws;             // 1 MiB packed W frags

    pack_w<<<128, 256, 0, stream>>>(gw, wpk);
    gemm_topk<<<T_TOK / 16, 512, 0, stream>>>(x, wpk, bias, out);
}

// Round 11
// 47.990 us; speedup vs baseline: 1.1554x; 1.1334x over previous
//
#include <hip/hip_runtime.h>
#include <math.h>
#include <stdint.h>

#define T_TOK 8192
#define DDIM  4096
#define NEXP  64
#define TOPK  8
#define MT    128       // tokens per block
#define BK    32        // k per 2-phase step
#define RS    2048.0f

typedef __attribute__((ext_vector_type(8))) _Float16 half8;
typedef __attribute__((ext_vector_type(4))) float f32x4;
typedef __attribute__((address_space(3))) uint32_t lds_u32;
typedef const __attribute__((address_space(1))) uint32_t glb_u32;

// ---- K0: pack gate_weight [E][D] f32 into MFMA B-fragment order, split f16.
// wpk[kt][ (n*2+p) ][lane*8 ..]: per kt (32 k), 4 n-frags x 2 planes x 512 f16.
// B frag (16x16x32): expert col = n*16 + (lane&15), k = kt*32 + (lane>>4)*8 + j.
__global__ __launch_bounds__(256) void pack_w(
    const float* __restrict__ gw, _Float16* __restrict__ wpk)
{
    const int g    = blockIdx.x * 256 + threadIdx.x;
    const int lane = g & 63;
    const int n    = (g >> 6) & 3;
    const int kt   = g >> 8;                     // 0..127
    const int e    = n * 16 + (lane & 15);
    const int k    = kt * 32 + (lane >> 4) * 8;

    const float* src = gw + (size_t)e * DDIM + k;
    float4 v0 = *reinterpret_cast<const float4*>(src);
    float4 v1 = *reinterpret_cast<const float4*>(src + 4);
    const float v[8] = {v0.x, v0.y, v0.z, v0.w, v1.x, v1.y, v1.z, v1.w};

    half8 h0, h1;
    #pragma unroll
    for (int j = 0; j < 8; j++) {
        _Float16 a = (_Float16)v[j];
        h0[j] = a;
        h1[j] = (_Float16)((v[j] - (float)a) * RS);
    }
    // chunk layout: wpk + kt*4096 + (n*2+p)*512 + lane*8
    _Float16* dst = wpk + (size_t)kt * 4096 + (size_t)(n * 2) * 512 + lane * 8;
    *reinterpret_cast<half8*>(dst)       = h0;
    *reinterpret_cast<half8*>(dst + 512) = h1;
}

// ---- K1: 2-phase LDS-staged MFMA partials (T3-minimum template) ----
// Block: 512 thr = 8 waves = 4 M-quarters x 2 N-halves; tile 128 tok x 64 exp,
// K-slice = STEPS*32.  Per step: global_load_lds stage A(16KB,src-swizzled)
// + B(8KB,linear) for t+1, compute t from LDS, __syncthreads drain.
template<int STEPS>
__global__ __launch_bounds__(512) void gemm_part(
    const float* __restrict__ x, const _Float16* __restrict__ wpk,
    float* __restrict__ part)
{
    __shared__ float    A[2][MT * BK];           // 2 x 16 KB
    __shared__ _Float16 B[2][4096];              // 2 x 8 KB

    const int tid  = threadIdx.x;
    const int lane = tid & 63;
    const int wv   = tid >> 6;
    const int wm   = wv & 3;                     // M-quarter (32 rows)
    const int wn   = wv >> 2;                    // N-half (32 experts)
    const int mt   = blockIdx.x & 63;
    const int slc  = blockIdx.x >> 6;
    const int m0   = mt * MT;
    const int kt0  = slc * STEPS;                // global kt base (32-k units)
    const int am   = lane & 15;
    const int ag   = lane >> 4;

    // staging map (per thread, r=0,1): float4 idx over A tile
    //   row = idx>>3, c = idx&7; src col4 pre-swizzled c ^ (row&7)
    const int s_row0 = tid >> 3;                 // r=0 rows 0..63
    const int s_c    = tid & 7;

#define STAGE(buf_, t_) do {                                                   \
        const size_t koff = (size_t)(kt0 + (t_)) * BK;                         \
        {   /* A: rows s_row0, s_row0+64 */                                    \
            int c0 = s_c ^ (s_row0 & 7);                                       \
            __builtin_amdgcn_global_load_lds(                                  \
                (glb_u32*)(x + (size_t)(m0 + s_row0) * DDIM + koff + c0 * 4),  \
                (lds_u32*)(&A[buf_][tid * 4]), 16, 0, 0);                      \
            int r1 = s_row0 + 64;                                              \
            int c1 = s_c ^ (r1 & 7);                                           \
            __builtin_amdgcn_global_load_lds(                                  \
                (glb_u32*)(x + (size_t)(m0 + r1) * DDIM + koff + c1 * 4),      \
                (lds_u32*)(&A[buf_][2048 + tid * 4]), 16, 0, 0);               \
        }                                                                      \
        {   /* B: linear 8 KB chunk for kt */                                  \
            const _Float16* bs = wpk + (size_t)(kt0 + (t_)) * 4096 + tid * 8;  \
            __builtin_amdgcn_global_load_lds(                                  \
                (glb_u32*)bs, (lds_u32*)(&B[buf_][tid * 8]), 16, 0, 0);        \
        }                                                                      \
    } while (0)

    f32x4 aH[2][2], aM[2][2];                    // [m-frag][n-frag]
    #pragma unroll
    for (int f = 0; f < 2; f++)
        #pragma unroll
        for (int n = 0; n < 2; n++) {
            aH[f][n] = (f32x4){0.f, 0.f, 0.f, 0.f};
            aM[f][n] = (f32x4){0.f, 0.f, 0.f, 0.f};
        }

    STAGE(0, 0);
    __syncthreads();                             // drain: buf0 ready

    #pragma unroll 2
    for (int t = 0; t < STEPS; t++) {
        const int buf = t & 1;
        if (t + 1 < STEPS) STAGE(buf ^ 1, t + 1);    // issue next (async FIFO)

        // ---- B frags from LDS (per-lane linear -> conflict-free) ----
        half8 B0[2], B1[2];
        #pragma unroll
        for (int nf = 0; nf < 2; nf++) {
            const int nb = ((wn * 2 + nf) * 2) * 512 + lane * 8;
            B0[nf] = *reinterpret_cast<const half8*>(&B[buf][nb]);
            B1[nf] = *reinterpret_cast<const half8*>(&B[buf][nb + 512]);
        }

        // ---- A frags: row = wm*32 + f*16 + am, k = ag*8..+8 ----
        // stored swizzled at 16B granularity: slot' = slot ^ (row&7)
        #pragma unroll
        for (int f = 0; f < 2; f++) {
            const int row = wm * 32 + f * 16 + am;
            const int sw  = am & 7;              // row&7 == am&7 here
            float4 alo = *reinterpret_cast<const float4*>(
                &A[buf][row * BK + ((ag * 2 + 0) ^ sw) * 4]);
            float4 ahi = *reinterpret_cast<const float4*>(
                &A[buf][row * BK + ((ag * 2 + 1) ^ sw) * 4]);
            const float vv[8] = {alo.x, alo.y, alo.z, alo.w,
                                 ahi.x, ahi.y, ahi.z, ahi.w};
            half8 a0, a1;
            #pragma unroll
            for (int j = 0; j < 8; j++) {
                float v = vv[j];
                _Float16 h = (_Float16)v;
                a0[j] = h;
                a1[j] = (_Float16)((v - (float)h) * RS);
            }
            #pragma unroll
            for (int nf = 0; nf < 2; nf++) {
                aH[f][nf] = __builtin_amdgcn_mfma_f32_16x16x32_f16(a0, B0[nf], aH[f][nf], 0, 0, 0);
                aM[f][nf] = __builtin_amdgcn_mfma_f32_16x16x32_f16(a0, B1[nf], aM[f][nf], 0, 0, 0);
                aM[f][nf] = __builtin_amdgcn_mfma_f32_16x16x32_f16(a1, B0[nf], aM[f][nf], 0, 0, 0);
            }
        }
        __syncthreads();                         // drain stage(t+1) + ds_reads
    }
#undef STAGE

    // ---- write partials: part[slc][token][expert] ----
    // C/D layout (m89): col = lane&15 (expert), row = (lane>>4)*4 + r (token)
    const float i1 = 1.0f / RS;
    float* po = part + (size_t)slc * T_TOK * NEXP + (size_t)m0 * NEXP;
    #pragma unroll
    for (int f = 0; f < 2; f++)
        #pragma unroll
        for (int nf = 0; nf < 2; nf++)
            #pragma unroll
            for (int r = 0; r < 4; r++)
                po[(size_t)(wm * 32 + f * 16 + ag * 4 + r) * NEXP
                   + (wn * 2 + nf) * 16 + am]
                    = aH[f][nf][r] + aM[f][nf][r] * i1;
}

// ---- K2: reduce partials, sigmoid, +bias, top-8, normalize ----
// Token swizzle keeps reader XCD == writer XCD for partial locality.
__global__ __launch_bounds__(256) void reduce_topk(
    const float* __restrict__ part, const float* __restrict__ bias,
    float* __restrict__ out, int S)
{
    const int wave = threadIdx.x >> 6;
    const int lane = threadIdx.x & 63;
    const int j    = blockIdx.x;                 // 0..2047
    const int g    = j & 7;
    const int q    = j >> 3;
    const int token = g * 128 + (q & 31) * 4 + (q >> 5) * 1024 + wave;
    if (token >= T_TOK) return;

    float logit = 0.f;
    for (int s = 0; s < S; s++)
        logit += part[(size_t)s * T_TOK * NEXP + (size_t)token * NEXP + lane];

    float score  = 1.f / (1.f + expf(-logit));
    float biased = score + bias[lane];

    float my_sc = 0.f;
    int   my_idx = 0;
    float ssum  = 0.f;

    #pragma unroll
    for (int jj = 0; jj < TOPK; jj++) {
        float v = biased;
        int   i = lane;
        #pragma unroll
        for (int off = 32; off >= 1; off >>= 1) {
            float ov = __shfl_xor(v, off);
            int   oi = __shfl_xor(i, off);
            if (ov > v || (ov == v && oi < i)) { v = ov; i = oi; }
        }
        float s_sel = __shfl(score, i);
        ssum += s_sel;
        if (lane == jj) { my_idx = i; my_sc = s_sel; }
        if (lane == i) biased = -INFINITY;
    }

    if (lane < TOPK) {
        out[(size_t)token * TOPK + lane] = (float)my_idx;                 // indices as f32
        out[(size_t)T_TOK * TOPK + (size_t)token * TOPK + lane]
            = my_sc / (ssum + 1e-20f);                                    // weights
    }
}

extern "C" void kernel_launch(void* const* d_in, const int* in_sizes, int n_in,
                              void* d_out, int out_size, void* d_ws, size_t ws_size,
                              hipStream_t stream) {
    (void)in_sizes; (void)n_in; (void)out_size;
    const float* x    = (const float*)d_in[0];
    const float* gw   = (const float*)d_in[1];
    const float* bias = (const float*)d_in[2];
    float* out = (float*)d_out;
    _Float16* wpk = (_Float16*)d_ws;                         // 1 MiB packed W frags
    float* part = (float*)(wpk + (size_t)DDIM * NEXP * 2);   // S x [T][E] f32

    const size_t wpk_bytes = (size_t)DDIM * NEXP * 2 * sizeof(_Float16);
    const size_t per_slice = (size_t)T_TOK * NEXP * sizeof(float);       // 2 MiB
    int S = 1;
    for (int cand : {8, 4, 2}) {
        if (wpk_bytes + (size_t)cand * per_slice <= ws_size) { S = cand; break; }
    }

    pack_w<<<128, 256, 0, stream>>>(gw, wpk);

    dim3 b1(512);
    switch (S) {
        case 8: gemm_part<16><<<dim3(64 * 8), b1, 0, stream>>>(x, wpk, part); break;
        case 4: gemm_part<32><<<dim3(64 * 4), b1, 0, stream>>>(x, wpk, part); break;
        case 2: gemm_part<64><<<dim3(64 * 2), b1, 0, stream>>>(x, wpk, part); break;
        default: gemm_part<128><<<dim3(64), b1, 0, stream>>>(x, wpk, part); break;
    }

    reduce_topk<<<dim3(T_TOK / 4), 256, 0, stream>>>(part, bias, out, S);
}